// Round 5
// baseline (239.184 us; speedup 1.0000x reference)
//
#include <hip/hip_runtime.h>

#define B_ 8
#define C_ 128
#define CI_ 64
#define N_ 4096

typedef _Float16 f16x8 __attribute__((ext_vector_type(8)));
typedef _Float16 f16x4 __attribute__((ext_vector_type(4)));
typedef float   f32x4  __attribute__((ext_vector_type(4)));

// ---------------------------------------------------------------------------
// K0: transpose x [B][C][N] fp32 -> xT [B][N][C] f16 (64x64 LDS tiles)
// ---------------------------------------------------------------------------
__global__ __launch_bounds__(256) void k_transpose(const float* __restrict__ x,
                                                   _Float16* __restrict__ xT)
{
    __shared__ float tile[64][65];
    int b = blockIdx.z, c0 = blockIdx.y * 64, n0 = blockIdx.x * 64;
    int tx = threadIdx.x & 63, ty = threadIdx.x >> 6;
#pragma unroll
    for (int i = 0; i < 16; i++) {
        int c = ty + i * 4;
        tile[c][tx] = x[((size_t)b * C_ + c0 + c) * N_ + n0 + tx];
    }
    __syncthreads();
#pragma unroll
    for (int i = 0; i < 16; i++) {
        int n = ty + i * 4;
        xT[((size_t)b * N_ + n0 + n) * C_ + c0 + tx] = (_Float16)tile[tx][n];
    }
}

// ---------------------------------------------------------------------------
// K0b: convert the four weight matrices fp32 -> f16 (each 8192 elems)
// ---------------------------------------------------------------------------
__global__ __launch_bounds__(256) void k_wconv(
    const float* __restrict__ thw, const float* __restrict__ phw,
    const float* __restrict__ gw,  const float* __restrict__ ww,
    _Float16* __restrict__ wTh, _Float16* __restrict__ wPh,
    _Float16* __restrict__ wG,  _Float16* __restrict__ wW)
{
    int i = blockIdx.x * 256 + threadIdx.x;   // 0..32767
    int which = i >> 13, j = i & 8191;
    if (which == 0)      wTh[j] = (_Float16)thw[j];
    else if (which == 1) wPh[j] = (_Float16)phw[j];
    else if (which == 2) wG[j]  = (_Float16)gw[j];
    else                 wW[j]  = (_Float16)ww[j];
}

// ---------------------------------------------------------------------------
// K1: projections -> th [B][N][CI] (PRE-SCALED by log2(e); th only feeds
// scores), ph [B][N][CI], gT [B][CI][N] (all f16)
// ---------------------------------------------------------------------------
__global__ __launch_bounds__(256) void k_proj(
    const _Float16* __restrict__ xT,
    const _Float16* __restrict__ wTh, const _Float16* __restrict__ wPh,
    const _Float16* __restrict__ wG,
    const float* __restrict__ bTh, const float* __restrict__ bPh,
    const float* __restrict__ bG,
    _Float16* __restrict__ th, _Float16* __restrict__ ph,
    _Float16* __restrict__ gT)
{
    const float kLog2e = 1.44269504088896f;
    int b = blockIdx.y, n0 = blockIdx.x * 64;
    int tid = threadIdx.x, wave = tid >> 6, lane = tid & 63;
    int l16 = lane & 15, quad = lane >> 4;
    const _Float16* xTb = xT + (size_t)b * N_ * C_;
    const _Float16* aRow = xTb + (size_t)(n0 + wave * 16 + l16) * C_ + quad * 8;

#pragma unroll
    for (int p = 0; p < 2; p++) {
        const _Float16* w = p ? wPh : wTh;
        const float* bias = p ? bPh : bTh;
        _Float16* outp = p ? ph : th;
        float scale = p ? 1.0f : kLog2e;
        f32x4 acc[4] = {};
#pragma unroll
        for (int kc = 0; kc < 4; kc++) {
            f16x8 a = *(const f16x8*)(aRow + kc * 32);
#pragma unroll
            for (int t = 0; t < 4; t++) {
                f16x8 bb = *(const f16x8*)(w + (size_t)(t * 16 + l16) * C_ + kc * 32 + quad * 8);
                acc[t] = __builtin_amdgcn_mfma_f32_16x16x32_f16(a, bb, acc[t], 0, 0, 0);
            }
        }
#pragma unroll
        for (int t = 0; t < 4; t++) {
            float bv = bias[t * 16 + l16];
#pragma unroll
            for (int r = 0; r < 4; r++) {
                int n = n0 + wave * 16 + quad * 4 + r;
                outp[((size_t)b * N_ + n) * CI_ + t * 16 + l16] = (_Float16)((acc[t][r] + bv) * scale);
            }
        }
    }
    {
        f32x4 acc[4] = {};
#pragma unroll
        for (int kc = 0; kc < 4; kc++) {
            f16x8 a = *(const f16x8*)(wG + (size_t)(wave * 16 + l16) * C_ + kc * 32 + quad * 8);
#pragma unroll
            for (int t = 0; t < 4; t++) {
                f16x8 bb = *(const f16x8*)(xTb + (size_t)(n0 + t * 16 + l16) * C_ + kc * 32 + quad * 8);
                acc[t] = __builtin_amdgcn_mfma_f32_16x16x32_f16(a, bb, acc[t], 0, 0, 0);
            }
        }
#pragma unroll
        for (int t = 0; t < 4; t++) {
#pragma unroll
            for (int r = 0; r < 4; r++) {
                int ci = wave * 16 + quad * 4 + r;
                gT[((size_t)b * CI_ + ci) * N_ + n0 + t * 16 + l16] = (_Float16)(acc[t][r] + bG[ci]);
            }
        }
    }
}

// ---------------------------------------------------------------------------
// K2a: nl2d[b][m] = -log2( sum_n exp2(S[n][m]) ), S = th(scaled)·ph^T.
// 512 threads: 8 waves each stream a 512-row n-slice (32 chunks of 16 rows),
// register-prefetched; quad shuffle + LDS reduce.
// ---------------------------------------------------------------------------
__global__ __launch_bounds__(512) void k_stats(
    const _Float16* __restrict__ th, const _Float16* __restrict__ ph,
    float* __restrict__ nl2d)
{
    __shared__ float Dp[8][64];
    int b = blockIdx.y, m0 = blockIdx.x * 64;
    int tid = threadIdx.x, wave = tid >> 6, lane = tid & 63;
    int l16 = lane & 15, quad = lane >> 4;
    const _Float16* thb = th + (size_t)b * N_ * CI_;
    const _Float16* phb = ph + (size_t)b * N_ * CI_;

    f16x8 Bp[4][2];                      // phi rows m0..m0+63 (B operands)
#pragma unroll
    for (int t = 0; t < 4; t++) {
        const _Float16* bp = phb + (size_t)(m0 + t * 16 + l16) * CI_ + quad * 8;
        Bp[t][0] = *(const f16x8*)(bp);
        Bp[t][1] = *(const f16x8*)(bp + 32);
    }
    float csum[4] = {0.f, 0.f, 0.f, 0.f};
    const _Float16* pA = thb + (size_t)(wave * 512 + l16) * CI_ + quad * 8;
    f16x8 A0 = *(const f16x8*)pA, A1 = *(const f16x8*)(pA + 32);
    for (int nc = 0; nc < 32; nc++) {
        const _Float16* pN = pA + ((nc < 31) ? 16 * CI_ : 0);
        f16x8 nA0 = *(const f16x8*)pN, nA1 = *(const f16x8*)(pN + 32);
        pA = pN;
#pragma unroll
        for (int t = 0; t < 4; t++) {
            f32x4 s = {0.f, 0.f, 0.f, 0.f};
            s = __builtin_amdgcn_mfma_f32_16x16x32_f16(A0, Bp[t][0], s, 0, 0, 0);
            s = __builtin_amdgcn_mfma_f32_16x16x32_f16(A1, Bp[t][1], s, 0, 0, 0);
            csum[t] += __builtin_amdgcn_exp2f(s[0]) + __builtin_amdgcn_exp2f(s[1])
                     + __builtin_amdgcn_exp2f(s[2]) + __builtin_amdgcn_exp2f(s[3]);
        }
        A0 = nA0; A1 = nA1;
    }
#pragma unroll
    for (int t = 0; t < 4; t++) {
        float s = csum[t];
        s += __shfl_xor(s, 16);
        s += __shfl_xor(s, 32);
        if (quad == 0) Dp[wave][t * 16 + l16] = s;
    }
    __syncthreads();
    if (tid < 64) {
        float d = Dp[0][tid] + Dp[1][tid] + Dp[2][tid] + Dp[3][tid]
                + Dp[4][tid] + Dp[5][tid] + Dp[6][tid] + Dp[7][tid];
        nl2d[(size_t)b * N_ + m0 + tid] = -__builtin_amdgcn_logf(d);   // v_log_f32 = log2
    }
}

// ---------------------------------------------------------------------------
// K2b: Y^T = g · softmax-weights.  S^T = ph·th^T with the accumulator
// INITIALIZED to -log2(D[m]) (bias folded into MFMA C operand), so
// P = exp2(S^T) directly; P stays in registers as the 16x16x16 B operand.
// 512 threads: 8 waves, each owns a 512-col m-slice (32 chunks); 4-slot LDS
// tree reduction (2 barriers).
// ---------------------------------------------------------------------------
__global__ __launch_bounds__(512) void k_attn(
    const _Float16* __restrict__ th, const _Float16* __restrict__ ph,
    const _Float16* __restrict__ gT, const float* __restrict__ nl2d,
    _Float16* __restrict__ Yf)
{
    __shared__ float red[4][4096];       // 4 x 16 KiB reduction slots
    int b = blockIdx.y, n0 = blockIdx.x * 64;
    int tid = threadIdx.x, wave = tid >> 6, lane = tid & 63;
    int l16 = lane & 15, quad = lane >> 4;
    const _Float16* thb = th + (size_t)b * N_ * CI_;
    const _Float16* phb = ph + (size_t)b * N_ * CI_;
    const _Float16* gTb = gT + (size_t)b * CI_ * N_;
    const float*    nlb = nl2d + (size_t)b * N_;

    f16x8 Bt[4][2];                      // theta rows n0..n0+63 (fixed B ops)
#pragma unroll
    for (int nt = 0; nt < 4; nt++) {
        const _Float16* bp = thb + (size_t)(n0 + nt * 16 + l16) * CI_ + quad * 8;
        Bt[nt][0] = *(const f16x8*)(bp);
        Bt[nt][1] = *(const f16x8*)(bp + 32);
    }
    f32x4 Y[4][4] = {};                  // [ci_tile][n_tile]

    const int m0 = wave * 512;
    const _Float16* pA = phb + (size_t)(m0 + l16) * CI_ + quad * 8;
    const _Float16* pG0 = gTb + (size_t)(l16) * N_ + m0 + quad * 4;
    f16x8 A0 = *(const f16x8*)pA, A1 = *(const f16x8*)(pA + 32);
    f32x4 z = *(const f32x4*)(nlb + m0 + quad * 4);
    f16x4 gf[4];
#pragma unroll
    for (int ct = 0; ct < 4; ct++)
        gf[ct] = *(const f16x4*)(pG0 + (size_t)(ct * 16) * N_);

    for (int mc = 0; mc < 32; mc++) {
        int step = (mc < 31) ? 16 : 0;
        const _Float16* pAn = pA + (size_t)step * CI_;
        f16x8 nA0 = *(const f16x8*)pAn, nA1 = *(const f16x8*)(pAn + 32);
        f32x4 nz = *(const f32x4*)(nlb + m0 + mc * 16 + step + quad * 4);
        const _Float16* pGn = pG0 + mc * 16 + step;
        f16x4 ngf[4];
#pragma unroll
        for (int ct = 0; ct < 4; ct++)
            ngf[ct] = *(const f16x4*)(pGn + (size_t)(ct * 16) * N_);
        pA = pAn;

        f32x4 S[4];
#pragma unroll
        for (int nt = 0; nt < 4; nt++) {
            f32x4 acc = z;               // bias: -log2(D[m]) folded into C
            acc = __builtin_amdgcn_mfma_f32_16x16x32_f16(A0, Bt[nt][0], acc, 0, 0, 0);
            S[nt] = __builtin_amdgcn_mfma_f32_16x16x32_f16(A1, Bt[nt][1], acc, 0, 0, 0);
        }
        f16x4 P[4];
#pragma unroll
        for (int nt = 0; nt < 4; nt++)
#pragma unroll
            for (int r = 0; r < 4; r++)
                P[nt][r] = (_Float16)__builtin_amdgcn_exp2f(S[nt][r]);
#pragma unroll
        for (int ct = 0; ct < 4; ct++)
#pragma unroll
            for (int nt = 0; nt < 4; nt++)
                Y[ct][nt] = __builtin_amdgcn_mfma_f32_16x16x16f16(gf[ct], P[nt], Y[ct][nt], 0, 0, 0);

        A0 = nA0; A1 = nA1; z = nz;
#pragma unroll
        for (int ct = 0; ct < 4; ct++) gf[ct] = ngf[ct];
    }

    // ---- cross-wave reduction: waves 4-7 dump, waves 0-3 add, store sums ---
    if (wave >= 4) {
        float* s = &red[wave - 4][lane * 4];
#pragma unroll
        for (int ct = 0; ct < 4; ct++)
#pragma unroll
            for (int nt = 0; nt < 4; nt++)
                *(f32x4*)(s + (ct * 4 + nt) * 256) = Y[ct][nt];
    }
    __syncthreads();
    if (wave < 4) {
        float* s = &red[wave][lane * 4];
#pragma unroll
        for (int ct = 0; ct < 4; ct++)
#pragma unroll
            for (int nt = 0; nt < 4; nt++) {
                Y[ct][nt] += *(const f32x4*)(s + (ct * 4 + nt) * 256);
                *(f32x4*)(s + (ct * 4 + nt) * 256) = Y[ct][nt];
            }
    }
    __syncthreads();
    // cooperative store: thread t -> row n = t>>3, ci group = (t&7)*8
    {
        int n = tid >> 3, k8 = tid & 7;
        _Float16 vals[8];
#pragma unroll
        for (int j = 0; j < 8; j++) {
            int ci = k8 * 8 + j;
            int ct = ci >> 4, jj = ci & 15, q = jj >> 2, r = jj & 3;
            int idx = (ct * 4 + (n >> 4)) * 256 + (q * 16 + (n & 15)) * 4 + r;
            vals[j] = (_Float16)(red[0][idx] + red[1][idx] + red[2][idx] + red[3][idx]);
        }
        *(f16x8*)(Yf + ((size_t)b * N_ + n0 + n) * CI_ + k8 * 8) = *(f16x8*)vals;
    }
}

// ---------------------------------------------------------------------------
// K3: out[b][c][n] = W_w @ Y^T + W_b + x (residual).
// ---------------------------------------------------------------------------
__global__ __launch_bounds__(256) void k_out(
    const _Float16* __restrict__ wW, const float* __restrict__ Wb,
    const _Float16* __restrict__ Yf, const float* __restrict__ x,
    float* __restrict__ out)
{
    int b = blockIdx.y, n0 = blockIdx.x * 64;
    int tid = threadIdx.x, wave = tid >> 6, lane = tid & 63;
    int l16 = lane & 15, quad = lane >> 4;
    f16x8 Af[2][2];
#pragma unroll
    for (int rt = 0; rt < 2; rt++)
#pragma unroll
        for (int kc = 0; kc < 2; kc++)
            Af[rt][kc] = *(const f16x8*)(wW + (size_t)(wave * 32 + rt * 16 + l16) * CI_ + kc * 32 + quad * 8);
    f32x4 acc[2][4] = {};
#pragma unroll
    for (int t = 0; t < 4; t++) {
        const _Float16* yp = Yf + ((size_t)b * N_ + n0 + t * 16 + l16) * CI_;
        f16x8 b0 = *(const f16x8*)(yp + quad * 8);
        f16x8 b1 = *(const f16x8*)(yp + 32 + quad * 8);
#pragma unroll
        for (int rt = 0; rt < 2; rt++) {
            acc[rt][t] = __builtin_amdgcn_mfma_f32_16x16x32_f16(Af[rt][0], b0, acc[rt][t], 0, 0, 0);
            acc[rt][t] = __builtin_amdgcn_mfma_f32_16x16x32_f16(Af[rt][1], b1, acc[rt][t], 0, 0, 0);
        }
    }
#pragma unroll
    for (int rt = 0; rt < 2; rt++)
#pragma unroll
        for (int t = 0; t < 4; t++)
#pragma unroll
            for (int r = 0; r < 4; r++) {
                int c = wave * 32 + rt * 16 + quad * 4 + r;
                size_t o = ((size_t)b * C_ + c) * N_ + n0 + t * 16 + l16;
                out[o] = acc[rt][t][r] + Wb[c] + x[o];
            }
}

// ---------------------------------------------------------------------------
extern "C" void kernel_launch(void* const* d_in, const int* in_sizes, int n_in,
                              void* d_out, int out_size, void* d_ws, size_t ws_size,
                              hipStream_t stream)
{
    const float* x    = (const float*)d_in[0];
    const float* g_w  = (const float*)d_in[1];
    const float* g_b  = (const float*)d_in[2];
    const float* th_w = (const float*)d_in[3];
    const float* th_b = (const float*)d_in[4];
    const float* ph_w = (const float*)d_in[5];
    const float* ph_b = (const float*)d_in[6];
    const float* W_w  = (const float*)d_in[7];
    const float* W_b  = (const float*)d_in[8];
    float* out = (float*)d_out;

    char* ws = (char*)d_ws;
    _Float16* xT  = (_Float16*)(ws);                  // [B][N][C]  8 MiB
    _Float16* th  = (_Float16*)(ws + 8388608);        // [B][N][CI] 4 MiB
    _Float16* ph  = (_Float16*)(ws + 12582912);       // [B][N][CI] 4 MiB
    _Float16* gT  = (_Float16*)(ws + 16777216);       // [B][CI][N] 4 MiB
    _Float16* Yf  = (_Float16*)(ws + 20971520);       // [B][N][CI] 4 MiB
    float*    nl2d= (float*)   (ws + 25165824);       // [B][N]     128 KiB
    _Float16* wTh = (_Float16*)(ws + 25296896);
    _Float16* wPh = (_Float16*)(ws + 25313280);
    _Float16* wG  = (_Float16*)(ws + 25329664);
    _Float16* wW  = (_Float16*)(ws + 25346048);       // end ~25.4 MiB

    hipLaunchKernelGGL(k_transpose, dim3(64, 2, 8), dim3(256), 0, stream, x, xT);
    hipLaunchKernelGGL(k_wconv, dim3(128), dim3(256), 0, stream,
                       th_w, ph_w, g_w, W_w, wTh, wPh, wG, wW);
    hipLaunchKernelGGL(k_proj, dim3(64, 8), dim3(256), 0, stream,
                       xT, wTh, wPh, wG, th_b, ph_b, g_b, th, ph, gT);
    hipLaunchKernelGGL(k_stats, dim3(64, 8), dim3(512), 0, stream, th, ph, nl2d);
    hipLaunchKernelGGL(k_attn, dim3(64, 8), dim3(512), 0, stream, th, ph, gT, nl2d, Yf);
    hipLaunchKernelGGL(k_out, dim3(64, 8), dim3(256), 0, stream, wW, W_b, Yf, x, out);
}

// Round 6
// 179.765 us; speedup vs baseline: 1.3305x; 1.3305x over previous
//
#include <hip/hip_runtime.h>

#define B_ 8
#define C_ 128
#define CI_ 64
#define N_ 4096

typedef _Float16 f16x8 __attribute__((ext_vector_type(8)));
typedef _Float16 f16x4 __attribute__((ext_vector_type(4)));
typedef float   f32x4  __attribute__((ext_vector_type(4)));

// Swizzled operand layouts (per batch, 256 chunks of 16 rows):
//  thS/phS: elem[((b*256+mc)*2 + half)*512 + lane*8 + e]
//           = X[row = mc*16 + (lane&15)][ci = half*32 + (lane>>4)*8 + e]
//    -> one f16x8 load per lane at (chunk_base + half*512 + lane*8) is a
//       fully-coalesced 1 KiB wave load = one MFMA A/B fragment.
//  gS:      elem[((b*256+mc)*64 + lane)*16 + ct*4 + j]
//           = g[ci = ct*16 + (lane&15)][m = mc*16 + (lane>>4)*4 + j]
//    -> two f16x8 loads per lane = all four PV A-fragments, coalesced.
// Chunk stride is 1024 elems in all three.

// ---------------------------------------------------------------------------
// K0: transpose x [B][C][N] fp32 -> xT [B][N][C] f16 (64x64 LDS tiles)
// ---------------------------------------------------------------------------
__global__ __launch_bounds__(256) void k_transpose(const float* __restrict__ x,
                                                   _Float16* __restrict__ xT)
{
    __shared__ float tile[64][65];
    int b = blockIdx.z, c0 = blockIdx.y * 64, n0 = blockIdx.x * 64;
    int tx = threadIdx.x & 63, ty = threadIdx.x >> 6;
#pragma unroll
    for (int i = 0; i < 16; i++) {
        int c = ty + i * 4;
        tile[c][tx] = x[((size_t)b * C_ + c0 + c) * N_ + n0 + tx];
    }
    __syncthreads();
#pragma unroll
    for (int i = 0; i < 16; i++) {
        int n = ty + i * 4;
        xT[((size_t)b * N_ + n0 + n) * C_ + c0 + tx] = (_Float16)tile[tx][n];
    }
}

// ---------------------------------------------------------------------------
// K0b: convert the four weight matrices fp32 -> f16 (each 8192 elems)
// ---------------------------------------------------------------------------
__global__ __launch_bounds__(256) void k_wconv(
    const float* __restrict__ thw, const float* __restrict__ phw,
    const float* __restrict__ gw,  const float* __restrict__ ww,
    _Float16* __restrict__ wTh, _Float16* __restrict__ wPh,
    _Float16* __restrict__ wG,  _Float16* __restrict__ wW)
{
    int i = blockIdx.x * 256 + threadIdx.x;   // 0..32767
    int which = i >> 13, j = i & 8191;
    if (which == 0)      wTh[j] = (_Float16)thw[j];
    else if (which == 1) wPh[j] = (_Float16)phw[j];
    else if (which == 2) wG[j]  = (_Float16)gw[j];
    else                 wW[j]  = (_Float16)ww[j];
}

// ---------------------------------------------------------------------------
// K1: projections -> thS (pre-scaled by log2e), phS, gS in swizzled layouts.
// ---------------------------------------------------------------------------
__global__ __launch_bounds__(256) void k_proj(
    const _Float16* __restrict__ xT,
    const _Float16* __restrict__ wTh, const _Float16* __restrict__ wPh,
    const _Float16* __restrict__ wG,
    const float* __restrict__ bTh, const float* __restrict__ bPh,
    const float* __restrict__ bG,
    _Float16* __restrict__ thS, _Float16* __restrict__ phS,
    _Float16* __restrict__ gS)
{
    const float kLog2e = 1.44269504088896f;
    int b = blockIdx.y, n0 = blockIdx.x * 64;
    int tid = threadIdx.x, wave = tid >> 6, lane = tid & 63;
    int l16 = lane & 15, quad = lane >> 4;
    const _Float16* xTb = xT + (size_t)b * N_ * C_;
    const _Float16* aRow = xTb + (size_t)(n0 + wave * 16 + l16) * C_ + quad * 8;

#pragma unroll
    for (int p = 0; p < 2; p++) {
        const _Float16* w = p ? wPh : wTh;
        const float* bias = p ? bPh : bTh;
        _Float16* outp = p ? phS : thS;
        float scale = p ? 1.0f : kLog2e;
        f32x4 acc[4] = {};
#pragma unroll
        for (int kc = 0; kc < 4; kc++) {
            f16x8 a = *(const f16x8*)(aRow + kc * 32);
#pragma unroll
            for (int t = 0; t < 4; t++) {
                f16x8 bb = *(const f16x8*)(w + (size_t)(t * 16 + l16) * C_ + kc * 32 + quad * 8);
                acc[t] = __builtin_amdgcn_mfma_f32_16x16x32_f16(a, bb, acc[t], 0, 0, 0);
            }
        }
        // value (row n = n0+wave*16+quad*4+r, col ci = t*16+l16) -> swizzle
#pragma unroll
        for (int t = 0; t < 4; t++) {
            float bv = bias[t * 16 + l16];
            int half = t >> 1;
            int q2 = (t & 1) * 2 + (l16 >> 3);
            int e = l16 & 7;
            size_t base = ((size_t)(b * 256 + (n0 >> 4) + wave) * 2 + half) * 512;
#pragma unroll
            for (int r = 0; r < 4; r++)
                outp[base + (q2 * 16 + quad * 4 + r) * 8 + e] =
                    (_Float16)((acc[t][r] + bv) * scale);
        }
    }
    {
        f32x4 acc[4] = {};
#pragma unroll
        for (int kc = 0; kc < 4; kc++) {
            f16x8 a = *(const f16x8*)(wG + (size_t)(wave * 16 + l16) * C_ + kc * 32 + quad * 8);
#pragma unroll
            for (int t = 0; t < 4; t++) {
                f16x8 bb = *(const f16x8*)(xTb + (size_t)(n0 + t * 16 + l16) * C_ + kc * 32 + quad * 8);
                acc[t] = __builtin_amdgcn_mfma_f32_16x16x32_f16(a, bb, acc[t], 0, 0, 0);
            }
        }
        // value (ci = wave*16+quad*4+r, m = n0+t*16+l16) -> gS swizzle
#pragma unroll
        for (int t = 0; t < 4; t++) {
            size_t base = (size_t)(b * 256 + (n0 >> 4) + t) * 1024;
#pragma unroll
            for (int r = 0; r < 4; r++) {
                int ci = wave * 16 + quad * 4 + r;
                gS[base + ((size_t)((l16 >> 2) * 16 + quad * 4 + r)) * 16 + wave * 4 + (l16 & 3)] =
                    (_Float16)(acc[t][r] + bG[ci]);
            }
        }
    }
}

// ---------------------------------------------------------------------------
// K2a: nl2d[b][m] = -log2( sum_n exp2(S[n][m]) ), S = th(scaled)·ph^T.
// All operand loads are coalesced 1 KiB fragment loads from thS/phS.
// ---------------------------------------------------------------------------
__global__ __launch_bounds__(512) void k_stats(
    const _Float16* __restrict__ thS, const _Float16* __restrict__ phS,
    float* __restrict__ nl2d)
{
    __shared__ float Dp[8][64];
    int b = blockIdx.y, m0 = blockIdx.x * 64;
    int tid = threadIdx.x, wave = tid >> 6, lane = tid & 63;
    int l16 = lane & 15, quad = lane >> 4;

    f16x8 Bp[4][2];                      // phi fragments for cols m0..m0+63
#pragma unroll
    for (int t = 0; t < 4; t++) {
        const _Float16* cb = phS + (size_t)(b * 256 + (m0 >> 4) + t) * 1024 + lane * 8;
        Bp[t][0] = *(const f16x8*)(cb);
        Bp[t][1] = *(const f16x8*)(cb + 512);
    }
    float csum[4] = {0.f, 0.f, 0.f, 0.f};
    const _Float16* pA = thS + (size_t)(b * 256 + wave * 32) * 1024 + lane * 8;
    f16x8 A0 = *(const f16x8*)pA, A1 = *(const f16x8*)(pA + 512);
    for (int nc = 0; nc < 32; nc++) {
        const _Float16* pN = pA + ((nc < 31) ? 1024 : 0);
        f16x8 nA0 = *(const f16x8*)pN, nA1 = *(const f16x8*)(pN + 512);
        pA = pN;
#pragma unroll
        for (int t = 0; t < 4; t++) {
            f32x4 s = {0.f, 0.f, 0.f, 0.f};
            s = __builtin_amdgcn_mfma_f32_16x16x32_f16(A0, Bp[t][0], s, 0, 0, 0);
            s = __builtin_amdgcn_mfma_f32_16x16x32_f16(A1, Bp[t][1], s, 0, 0, 0);
            csum[t] += __builtin_amdgcn_exp2f(s[0]) + __builtin_amdgcn_exp2f(s[1])
                     + __builtin_amdgcn_exp2f(s[2]) + __builtin_amdgcn_exp2f(s[3]);
        }
        A0 = nA0; A1 = nA1;
    }
#pragma unroll
    for (int t = 0; t < 4; t++) {
        float s = csum[t];
        s += __shfl_xor(s, 16);
        s += __shfl_xor(s, 32);
        if (quad == 0) Dp[wave][t * 16 + l16] = s;
    }
    __syncthreads();
    if (tid < 64) {
        float d = Dp[0][tid] + Dp[1][tid] + Dp[2][tid] + Dp[3][tid]
                + Dp[4][tid] + Dp[5][tid] + Dp[6][tid] + Dp[7][tid];
        nl2d[(size_t)b * N_ + m0 + tid] = -__builtin_amdgcn_logf(d);   // v_log_f32 = log2
    }
}

// ---------------------------------------------------------------------------
// K2b: Y^T = g · softmax-weights.  S^T = ph·th^T, acc init = -log2(D[m]);
// P = exp2(S^T) stays in registers as the 16x16x16 B operand.  All streamed
// loads (phi A-fragments, g PV-fragments) are coalesced from phS/gS.
// ---------------------------------------------------------------------------
__global__ __launch_bounds__(512) void k_attn(
    const _Float16* __restrict__ thS, const _Float16* __restrict__ phS,
    const _Float16* __restrict__ gS, const float* __restrict__ nl2d,
    _Float16* __restrict__ Yf)
{
    __shared__ float red[4][4096];       // 4 x 16 KiB reduction slots
    int b = blockIdx.y, n0 = blockIdx.x * 64;
    int tid = threadIdx.x, wave = tid >> 6, lane = tid & 63;
    int l16 = lane & 15, quad = lane >> 4;
    const float* nlb = nl2d + (size_t)b * N_;

    f16x8 Bt[4][2];                      // theta fragments rows n0..n0+63
#pragma unroll
    for (int nt = 0; nt < 4; nt++) {
        const _Float16* cb = thS + (size_t)(b * 256 + (n0 >> 4) + nt) * 1024 + lane * 8;
        Bt[nt][0] = *(const f16x8*)(cb);
        Bt[nt][1] = *(const f16x8*)(cb + 512);
    }
    f32x4 Y[4][4] = {};                  // [ci_tile][n_tile]

    const _Float16* pA = phS + (size_t)(b * 256 + wave * 32) * 1024 + lane * 8;
    const _Float16* pG = gS  + (size_t)(b * 256 + wave * 32) * 1024 + lane * 16;
    f16x8 A0 = *(const f16x8*)pA, A1 = *(const f16x8*)(pA + 512);
    f16x8 G0 = *(const f16x8*)pG, G1 = *(const f16x8*)(pG + 8);
    f32x4 z = *(const f32x4*)(nlb + wave * 512 + quad * 4);

    for (int mc = 0; mc < 32; mc++) {
        int step = (mc < 31) ? 1024 : 0;
        f16x8 nA0 = *(const f16x8*)(pA + step), nA1 = *(const f16x8*)(pA + step + 512);
        f16x8 nG0 = *(const f16x8*)(pG + step), nG1 = *(const f16x8*)(pG + step + 8);
        f32x4 nz = *(const f32x4*)(nlb + wave * 512 + mc * 16 + (step ? 16 : 0) + quad * 4);
        pA += step; pG += step;

        f32x4 S[4];
#pragma unroll
        for (int nt = 0; nt < 4; nt++) {
            f32x4 acc = z;               // bias: -log2(D[m]) folded into C
            acc = __builtin_amdgcn_mfma_f32_16x16x32_f16(A0, Bt[nt][0], acc, 0, 0, 0);
            S[nt] = __builtin_amdgcn_mfma_f32_16x16x32_f16(A1, Bt[nt][1], acc, 0, 0, 0);
        }
        f16x4 P[4];
#pragma unroll
        for (int nt = 0; nt < 4; nt++)
#pragma unroll
            for (int r = 0; r < 4; r++)
                P[nt][r] = (_Float16)__builtin_amdgcn_exp2f(S[nt][r]);

        f16x4 gf[4];
        gf[0] = __builtin_shufflevector(G0, G0, 0, 1, 2, 3);
        gf[1] = __builtin_shufflevector(G0, G0, 4, 5, 6, 7);
        gf[2] = __builtin_shufflevector(G1, G1, 0, 1, 2, 3);
        gf[3] = __builtin_shufflevector(G1, G1, 4, 5, 6, 7);
#pragma unroll
        for (int ct = 0; ct < 4; ct++)
#pragma unroll
            for (int nt = 0; nt < 4; nt++)
                Y[ct][nt] = __builtin_amdgcn_mfma_f32_16x16x16f16(gf[ct], P[nt], Y[ct][nt], 0, 0, 0);

        A0 = nA0; A1 = nA1; G0 = nG0; G1 = nG1; z = nz;
    }

    // ---- cross-wave reduction: waves 4-7 dump, waves 0-3 add, store sums ---
    if (wave >= 4) {
        float* s = &red[wave - 4][lane * 4];
#pragma unroll
        for (int ct = 0; ct < 4; ct++)
#pragma unroll
            for (int nt = 0; nt < 4; nt++)
                *(f32x4*)(s + (ct * 4 + nt) * 256) = Y[ct][nt];
    }
    __syncthreads();
    if (wave < 4) {
        float* s = &red[wave][lane * 4];
#pragma unroll
        for (int ct = 0; ct < 4; ct++)
#pragma unroll
            for (int nt = 0; nt < 4; nt++) {
                Y[ct][nt] += *(const f32x4*)(s + (ct * 4 + nt) * 256);
                *(f32x4*)(s + (ct * 4 + nt) * 256) = Y[ct][nt];
            }
    }
    __syncthreads();
    // cooperative store: thread t -> row n = t>>3, ci group = (t&7)*8
    {
        int n = tid >> 3, k8 = tid & 7;
        _Float16 vals[8];
#pragma unroll
        for (int j = 0; j < 8; j++) {
            int ci = k8 * 8 + j;
            int ct = ci >> 4, jj = ci & 15, q = jj >> 2, r = jj & 3;
            int idx = (ct * 4 + (n >> 4)) * 256 + (q * 16 + (n & 15)) * 4 + r;
            vals[j] = (_Float16)(red[0][idx] + red[1][idx] + red[2][idx] + red[3][idx]);
        }
        *(f16x8*)(Yf + ((size_t)b * N_ + n0 + n) * CI_ + k8 * 8) = *(f16x8*)vals;
    }
}

// ---------------------------------------------------------------------------
// K3: out[b][c][n] = W_w @ Y^T + W_b + x (residual).
// ---------------------------------------------------------------------------
__global__ __launch_bounds__(256) void k_out(
    const _Float16* __restrict__ wW, const float* __restrict__ Wb,
    const _Float16* __restrict__ Yf, const float* __restrict__ x,
    float* __restrict__ out)
{
    int b = blockIdx.y, n0 = blockIdx.x * 64;
    int tid = threadIdx.x, wave = tid >> 6, lane = tid & 63;
    int l16 = lane & 15, quad = lane >> 4;
    f16x8 Af[2][2];
#pragma unroll
    for (int rt = 0; rt < 2; rt++)
#pragma unroll
        for (int kc = 0; kc < 2; kc++)
            Af[rt][kc] = *(const f16x8*)(wW + (size_t)(wave * 32 + rt * 16 + l16) * CI_ + kc * 32 + quad * 8);
    f32x4 acc[2][4] = {};
#pragma unroll
    for (int t = 0; t < 4; t++) {
        const _Float16* yp = Yf + ((size_t)b * N_ + n0 + t * 16 + l16) * CI_;
        f16x8 b0 = *(const f16x8*)(yp + quad * 8);
        f16x8 b1 = *(const f16x8*)(yp + 32 + quad * 8);
#pragma unroll
        for (int rt = 0; rt < 2; rt++) {
            acc[rt][t] = __builtin_amdgcn_mfma_f32_16x16x32_f16(Af[rt][0], b0, acc[rt][t], 0, 0, 0);
            acc[rt][t] = __builtin_amdgcn_mfma_f32_16x16x32_f16(Af[rt][1], b1, acc[rt][t], 0, 0, 0);
        }
    }
#pragma unroll
    for (int rt = 0; rt < 2; rt++)
#pragma unroll
        for (int t = 0; t < 4; t++)
#pragma unroll
            for (int r = 0; r < 4; r++) {
                int c = wave * 32 + rt * 16 + quad * 4 + r;
                size_t o = ((size_t)b * C_ + c) * N_ + n0 + t * 16 + l16;
                out[o] = acc[rt][t][r] + Wb[c] + x[o];
            }
}

// ---------------------------------------------------------------------------
extern "C" void kernel_launch(void* const* d_in, const int* in_sizes, int n_in,
                              void* d_out, int out_size, void* d_ws, size_t ws_size,
                              hipStream_t stream)
{
    const float* x    = (const float*)d_in[0];
    const float* g_w  = (const float*)d_in[1];
    const float* g_b  = (const float*)d_in[2];
    const float* th_w = (const float*)d_in[3];
    const float* th_b = (const float*)d_in[4];
    const float* ph_w = (const float*)d_in[5];
    const float* ph_b = (const float*)d_in[6];
    const float* W_w  = (const float*)d_in[7];
    const float* W_b  = (const float*)d_in[8];
    float* out = (float*)d_out;

    char* ws = (char*)d_ws;
    _Float16* xT  = (_Float16*)(ws);                  // [B][N][C]  8 MiB
    _Float16* thS = (_Float16*)(ws + 8388608);        // swizzled   4 MiB
    _Float16* phS = (_Float16*)(ws + 12582912);       // swizzled   4 MiB
    _Float16* gS  = (_Float16*)(ws + 16777216);       // swizzled   4 MiB
    _Float16* Yf  = (_Float16*)(ws + 20971520);       // [B][N][CI] 4 MiB
    float*    nl2d= (float*)   (ws + 25165824);       // [B][N]     128 KiB
    _Float16* wTh = (_Float16*)(ws + 25296896);
    _Float16* wPh = (_Float16*)(ws + 25313280);
    _Float16* wG  = (_Float16*)(ws + 25329664);
    _Float16* wW  = (_Float16*)(ws + 25346048);       // end ~25.4 MiB

    hipLaunchKernelGGL(k_transpose, dim3(64, 2, 8), dim3(256), 0, stream, x, xT);
    hipLaunchKernelGGL(k_wconv, dim3(128), dim3(256), 0, stream,
                       th_w, ph_w, g_w, W_w, wTh, wPh, wG, wW);
    hipLaunchKernelGGL(k_proj, dim3(64, 8), dim3(256), 0, stream,
                       xT, wTh, wPh, wG, th_b, ph_b, g_b, thS, phS, gS);
    hipLaunchKernelGGL(k_stats, dim3(64, 8), dim3(512), 0, stream, thS, phS, nl2d);
    hipLaunchKernelGGL(k_attn, dim3(64, 8), dim3(512), 0, stream, thS, phS, gS, nl2d, Yf);
    hipLaunchKernelGGL(k_out, dim3(64, 8), dim3(256), 0, stream, wW, W_b, Yf, x, out);
}

// Round 7
// 178.948 us; speedup vs baseline: 1.3366x; 1.0046x over previous
//
#include <hip/hip_runtime.h>

#define B_ 8
#define C_ 128
#define CI_ 64
#define N_ 4096

typedef _Float16 f16x8 __attribute__((ext_vector_type(8)));
typedef _Float16 f16x4 __attribute__((ext_vector_type(4)));
typedef float   f32x4  __attribute__((ext_vector_type(4)));

// Swizzled operand layouts (per batch, 256 chunks of 16 rows):
//  thS/phS: elem[((b*256+mc)*2 + half)*512 + lane*8 + e]
//           = X[row = mc*16 + (lane&15)][ci = half*32 + (lane>>4)*8 + e]
//  gS:      elem[(b*256+mc)*1024 + lane*16 + (ct*4 + j)]
//           = g[ci = ct*16 + (lane&15)][m = mc*16 + (lane>>4)*4 + j]
// Chunk stride is 1024 elems in all three; every streamed wave load is a
// fully-coalesced 1 KiB dwordx4.

// ---------------------------------------------------------------------------
// K0: transpose x [B][C][N] fp32 -> xT [B][N][C] f16 (64x64 LDS tiles)
// ---------------------------------------------------------------------------
__global__ __launch_bounds__(256) void k_transpose(const float* __restrict__ x,
                                                   _Float16* __restrict__ xT)
{
    __shared__ float tile[64][65];
    int b = blockIdx.z, c0 = blockIdx.y * 64, n0 = blockIdx.x * 64;
    int tx = threadIdx.x & 63, ty = threadIdx.x >> 6;
#pragma unroll
    for (int i = 0; i < 16; i++) {
        int c = ty + i * 4;
        tile[c][tx] = x[((size_t)b * C_ + c0 + c) * N_ + n0 + tx];
    }
    __syncthreads();
#pragma unroll
    for (int i = 0; i < 16; i++) {
        int n = ty + i * 4;
        xT[((size_t)b * N_ + n0 + n) * C_ + c0 + tx] = (_Float16)tile[tx][n];
    }
}

// ---------------------------------------------------------------------------
// K0b: convert the four weight matrices fp32 -> f16 (each 8192 elems)
// ---------------------------------------------------------------------------
__global__ __launch_bounds__(256) void k_wconv(
    const float* __restrict__ thw, const float* __restrict__ phw,
    const float* __restrict__ gw,  const float* __restrict__ ww,
    _Float16* __restrict__ wTh, _Float16* __restrict__ wPh,
    _Float16* __restrict__ wG,  _Float16* __restrict__ wW)
{
    int i = blockIdx.x * 256 + threadIdx.x;   // 0..32767
    int which = i >> 13, j = i & 8191;
    if (which == 0)      wTh[j] = (_Float16)thw[j];
    else if (which == 1) wPh[j] = (_Float16)phw[j];
    else if (which == 2) wG[j]  = (_Float16)gw[j];
    else                 wW[j]  = (_Float16)ww[j];
}

// ---------------------------------------------------------------------------
// K1: projections -> thS (pre-scaled by log2e), phS, gS in swizzled layouts.
// ---------------------------------------------------------------------------
__global__ __launch_bounds__(256) void k_proj(
    const _Float16* __restrict__ xT,
    const _Float16* __restrict__ wTh, const _Float16* __restrict__ wPh,
    const _Float16* __restrict__ wG,
    const float* __restrict__ bTh, const float* __restrict__ bPh,
    const float* __restrict__ bG,
    _Float16* __restrict__ thS, _Float16* __restrict__ phS,
    _Float16* __restrict__ gS)
{
    const float kLog2e = 1.44269504088896f;
    int b = blockIdx.y, n0 = blockIdx.x * 64;
    int tid = threadIdx.x, wave = tid >> 6, lane = tid & 63;
    int l16 = lane & 15, quad = lane >> 4;
    const _Float16* xTb = xT + (size_t)b * N_ * C_;
    const _Float16* aRow = xTb + (size_t)(n0 + wave * 16 + l16) * C_ + quad * 8;

#pragma unroll
    for (int p = 0; p < 2; p++) {
        const _Float16* w = p ? wPh : wTh;
        const float* bias = p ? bPh : bTh;
        _Float16* outp = p ? phS : thS;
        float scale = p ? 1.0f : kLog2e;
        f32x4 acc[4] = {};
#pragma unroll
        for (int kc = 0; kc < 4; kc++) {
            f16x8 a = *(const f16x8*)(aRow + kc * 32);
#pragma unroll
            for (int t = 0; t < 4; t++) {
                f16x8 bb = *(const f16x8*)(w + (size_t)(t * 16 + l16) * C_ + kc * 32 + quad * 8);
                acc[t] = __builtin_amdgcn_mfma_f32_16x16x32_f16(a, bb, acc[t], 0, 0, 0);
            }
        }
        // value (row n = n0+wave*16+quad*4+r, col ci = t*16+l16) -> swizzle
#pragma unroll
        for (int t = 0; t < 4; t++) {
            float bv = bias[t * 16 + l16];
            int half = t >> 1;
            int q2 = (t & 1) * 2 + (l16 >> 3);
            int e = l16 & 7;
            size_t base = ((size_t)(b * 256 + (n0 >> 4) + wave) * 2 + half) * 512;
#pragma unroll
            for (int r = 0; r < 4; r++)
                outp[base + (q2 * 16 + quad * 4 + r) * 8 + e] =
                    (_Float16)((acc[t][r] + bv) * scale);
        }
    }
    {
        f32x4 acc[4] = {};
#pragma unroll
        for (int kc = 0; kc < 4; kc++) {
            f16x8 a = *(const f16x8*)(wG + (size_t)(wave * 16 + l16) * C_ + kc * 32 + quad * 8);
#pragma unroll
            for (int t = 0; t < 4; t++) {
                f16x8 bb = *(const f16x8*)(xTb + (size_t)(n0 + t * 16 + l16) * C_ + kc * 32 + quad * 8);
                acc[t] = __builtin_amdgcn_mfma_f32_16x16x32_f16(a, bb, acc[t], 0, 0, 0);
            }
        }
        // value (ci = wave*16+quad*4+r, m = n0+t*16+l16) -> gS swizzle
#pragma unroll
        for (int t = 0; t < 4; t++) {
            size_t base = (size_t)(b * 256 + (n0 >> 4) + t) * 1024;
#pragma unroll
            for (int r = 0; r < 4; r++) {
                int ci = wave * 16 + quad * 4 + r;
                gS[base + ((size_t)((l16 >> 2) * 16 + quad * 4 + r)) * 16 + wave * 4 + (l16 & 3)] =
                    (_Float16)(acc[t][r] + bG[ci]);
            }
        }
    }
}

// ---------------------------------------------------------------------------
// K2a: nl2d[b][m] = -log2( sum_n exp2(S[n][m]) ), S = th(scaled)·ph^T.
// Software-pipelined: issue QK MFMAs of chunk i, then do exp+accumulate on
// chunk i-1's scores (hides the MFMA->VALU dependency wait).
// ---------------------------------------------------------------------------
__global__ __launch_bounds__(512) void k_stats(
    const _Float16* __restrict__ thS, const _Float16* __restrict__ phS,
    float* __restrict__ nl2d)
{
    __shared__ float Dp[8][64];
    int b = blockIdx.y, m0 = blockIdx.x * 64;
    int tid = threadIdx.x, wave = tid >> 6, lane = tid & 63;
    int l16 = lane & 15, quad = lane >> 4;

    f16x8 Bp[4][2];                      // phi fragments for cols m0..m0+63
#pragma unroll
    for (int t = 0; t < 4; t++) {
        const _Float16* cb = phS + (size_t)(b * 256 + (m0 >> 4) + t) * 1024 + lane * 8;
        Bp[t][0] = *(const f16x8*)(cb);
        Bp[t][1] = *(const f16x8*)(cb + 512);
    }
    float csum[4] = {0.f, 0.f, 0.f, 0.f};
    const _Float16* pA = thS + (size_t)(b * 256 + wave * 32) * 1024 + lane * 8;
    f16x8 A0 = *(const f16x8*)pA, A1 = *(const f16x8*)(pA + 512);
    f32x4 Sp[4];
    {   // peel chunk 0: QK only
        const _Float16* pN = pA + 1024;
        f16x8 nA0 = *(const f16x8*)pN, nA1 = *(const f16x8*)(pN + 512);
        pA = pN;
#pragma unroll
        for (int t = 0; t < 4; t++) {
            f32x4 s = {0.f, 0.f, 0.f, 0.f};
            s = __builtin_amdgcn_mfma_f32_16x16x32_f16(A0, Bp[t][0], s, 0, 0, 0);
            Sp[t] = __builtin_amdgcn_mfma_f32_16x16x32_f16(A1, Bp[t][1], s, 0, 0, 0);
        }
        A0 = nA0; A1 = nA1;
    }
    for (int nc = 1; nc < 32; nc++) {
        const _Float16* pN = pA + ((nc < 31) ? 1024 : 0);
        f16x8 nA0 = *(const f16x8*)pN, nA1 = *(const f16x8*)(pN + 512);
        pA = pN;
        f32x4 Sc[4];
#pragma unroll
        for (int t = 0; t < 4; t++) {    // QK of chunk nc (issue first)
            f32x4 s = {0.f, 0.f, 0.f, 0.f};
            s = __builtin_amdgcn_mfma_f32_16x16x32_f16(A0, Bp[t][0], s, 0, 0, 0);
            Sc[t] = __builtin_amdgcn_mfma_f32_16x16x32_f16(A1, Bp[t][1], s, 0, 0, 0);
        }
#pragma unroll
        for (int t = 0; t < 4; t++) {    // exp+acc of chunk nc-1
            csum[t] += __builtin_amdgcn_exp2f(Sp[t][0]) + __builtin_amdgcn_exp2f(Sp[t][1])
                     + __builtin_amdgcn_exp2f(Sp[t][2]) + __builtin_amdgcn_exp2f(Sp[t][3]);
            Sp[t] = Sc[t];
        }
        A0 = nA0; A1 = nA1;
    }
#pragma unroll
    for (int t = 0; t < 4; t++)          // drain chunk 31
        csum[t] += __builtin_amdgcn_exp2f(Sp[t][0]) + __builtin_amdgcn_exp2f(Sp[t][1])
                 + __builtin_amdgcn_exp2f(Sp[t][2]) + __builtin_amdgcn_exp2f(Sp[t][3]);
#pragma unroll
    for (int t = 0; t < 4; t++) {
        float s = csum[t];
        s += __shfl_xor(s, 16);
        s += __shfl_xor(s, 32);
        if (quad == 0) Dp[wave][t * 16 + l16] = s;
    }
    __syncthreads();
    if (tid < 64) {
        float d = Dp[0][tid] + Dp[1][tid] + Dp[2][tid] + Dp[3][tid]
                + Dp[4][tid] + Dp[5][tid] + Dp[6][tid] + Dp[7][tid];
        nl2d[(size_t)b * N_ + m0 + tid] = -__builtin_amdgcn_logf(d);   // v_log_f32 = log2
    }
}

// ---------------------------------------------------------------------------
// K2b: Y^T = g · softmax-weights.  S^T = ph·th^T, acc init = -log2(D[m]);
// P = exp2(S^T) stays in registers as the 16x16x16 B operand.
// Software-pipelined with P-lag: per iteration issue QK(i) then PV(i-1)
// (24 independent MFMAs back-to-back), then exp(i) while other waves fill.
// ---------------------------------------------------------------------------
__global__ __launch_bounds__(512) void k_attn(
    const _Float16* __restrict__ thS, const _Float16* __restrict__ phS,
    const _Float16* __restrict__ gS, const float* __restrict__ nl2d,
    _Float16* __restrict__ Yf)
{
    __shared__ float red[4][4096];       // 4 x 16 KiB reduction slots
    int b = blockIdx.y, n0 = blockIdx.x * 64;
    int tid = threadIdx.x, wave = tid >> 6, lane = tid & 63;
    int l16 = lane & 15, quad = lane >> 4;
    const float* nlb = nl2d + (size_t)b * N_;

    f16x8 Bt[4][2];                      // theta fragments rows n0..n0+63
#pragma unroll
    for (int nt = 0; nt < 4; nt++) {
        const _Float16* cb = thS + (size_t)(b * 256 + (n0 >> 4) + nt) * 1024 + lane * 8;
        Bt[nt][0] = *(const f16x8*)(cb);
        Bt[nt][1] = *(const f16x8*)(cb + 512);
    }
    f32x4 Y[4][4] = {};                  // [ci_tile][n_tile]

    const int base = b * 256 + wave * 32;
    const _Float16* pA = phS + (size_t)base * 1024 + lane * 8;
    const _Float16* pG = gS  + (size_t)base * 1024 + lane * 16;
    const float*    pZ = nlb + wave * 512 + quad * 4;

    f16x8 A0 = *(const f16x8*)pA, A1 = *(const f16x8*)(pA + 512);
    f16x8 G0 = *(const f16x8*)pG, G1 = *(const f16x8*)(pG + 8);
    f32x4 z = *(const f32x4*)pZ;

    f16x4 Pp[4];                         // lagged P (chunk i-1)
    f16x8 Gp0, Gp1;                      // lagged G (chunk i-1)

    {   // peel chunk 0: prefetch 1, QK(0), exp -> Pp, lag G
        f16x8 nA0 = *(const f16x8*)(pA + 1024), nA1 = *(const f16x8*)(pA + 1536);
        f16x8 nG0 = *(const f16x8*)(pG + 1024), nG1 = *(const f16x8*)(pG + 1032);
        f32x4 nz = *(const f32x4*)(pZ + 16);
        f32x4 S[4];
#pragma unroll
        for (int nt = 0; nt < 4; nt++) {
            f32x4 acc = z;
            acc = __builtin_amdgcn_mfma_f32_16x16x32_f16(A0, Bt[nt][0], acc, 0, 0, 0);
            S[nt] = __builtin_amdgcn_mfma_f32_16x16x32_f16(A1, Bt[nt][1], acc, 0, 0, 0);
        }
#pragma unroll
        for (int nt = 0; nt < 4; nt++)
#pragma unroll
            for (int r = 0; r < 4; r++)
                Pp[nt][r] = (_Float16)__builtin_amdgcn_exp2f(S[nt][r]);
        Gp0 = G0; Gp1 = G1;
        A0 = nA0; A1 = nA1; G0 = nG0; G1 = nG1; z = nz;
        pA += 1024; pG += 1024; pZ += 16;
    }

    for (int mc = 1; mc < 32; mc++) {
        int step = (mc < 31) ? 1024 : 0;
        f16x8 nA0 = *(const f16x8*)(pA + step), nA1 = *(const f16x8*)(pA + step + 512);
        f16x8 nG0 = *(const f16x8*)(pG + step), nG1 = *(const f16x8*)(pG + step + 8);
        f32x4 nz = *(const f32x4*)(pZ + (step ? 16 : 0));
        pA += step; pG += step; pZ += (step ? 16 : 0);

        f32x4 S[4];
#pragma unroll
        for (int nt = 0; nt < 4; nt++) { // QK of chunk mc
            f32x4 acc = z;
            acc = __builtin_amdgcn_mfma_f32_16x16x32_f16(A0, Bt[nt][0], acc, 0, 0, 0);
            S[nt] = __builtin_amdgcn_mfma_f32_16x16x32_f16(A1, Bt[nt][1], acc, 0, 0, 0);
        }
        {   // PV of chunk mc-1 (independent of S -> fills MFMA pipe)
            f16x4 gf[4];
            gf[0] = __builtin_shufflevector(Gp0, Gp0, 0, 1, 2, 3);
            gf[1] = __builtin_shufflevector(Gp0, Gp0, 4, 5, 6, 7);
            gf[2] = __builtin_shufflevector(Gp1, Gp1, 0, 1, 2, 3);
            gf[3] = __builtin_shufflevector(Gp1, Gp1, 4, 5, 6, 7);
#pragma unroll
            for (int ct = 0; ct < 4; ct++)
#pragma unroll
                for (int nt = 0; nt < 4; nt++)
                    Y[ct][nt] = __builtin_amdgcn_mfma_f32_16x16x16f16(gf[ct], Pp[nt], Y[ct][nt], 0, 0, 0);
        }
#pragma unroll
        for (int nt = 0; nt < 4; nt++)   // exp of chunk mc
#pragma unroll
            for (int r = 0; r < 4; r++)
                Pp[nt][r] = (_Float16)__builtin_amdgcn_exp2f(S[nt][r]);
        Gp0 = G0; Gp1 = G1;
        A0 = nA0; A1 = nA1; G0 = nG0; G1 = nG1; z = nz;
    }
    {   // drain: PV of chunk 31
        f16x4 gf[4];
        gf[0] = __builtin_shufflevector(Gp0, Gp0, 0, 1, 2, 3);
        gf[1] = __builtin_shufflevector(Gp0, Gp0, 4, 5, 6, 7);
        gf[2] = __builtin_shufflevector(Gp1, Gp1, 0, 1, 2, 3);
        gf[3] = __builtin_shufflevector(Gp1, Gp1, 4, 5, 6, 7);
#pragma unroll
        for (int ct = 0; ct < 4; ct++)
#pragma unroll
            for (int nt = 0; nt < 4; nt++)
                Y[ct][nt] = __builtin_amdgcn_mfma_f32_16x16x16f16(gf[ct], Pp[nt], Y[ct][nt], 0, 0, 0);
    }

    // ---- cross-wave reduction: waves 4-7 dump, waves 0-3 add, store sums ---
    if (wave >= 4) {
        float* s = &red[wave - 4][lane * 4];
#pragma unroll
        for (int ct = 0; ct < 4; ct++)
#pragma unroll
            for (int nt = 0; nt < 4; nt++)
                *(f32x4*)(s + (ct * 4 + nt) * 256) = Y[ct][nt];
    }
    __syncthreads();
    if (wave < 4) {
        float* s = &red[wave][lane * 4];
#pragma unroll
        for (int ct = 0; ct < 4; ct++)
#pragma unroll
            for (int nt = 0; nt < 4; nt++) {
                Y[ct][nt] += *(const f32x4*)(s + (ct * 4 + nt) * 256);
                *(f32x4*)(s + (ct * 4 + nt) * 256) = Y[ct][nt];
            }
    }
    __syncthreads();
    // cooperative store: thread t -> row n = t>>3, ci group = (t&7)*8
    {
        int n = tid >> 3, k8 = tid & 7;
        _Float16 vals[8];
#pragma unroll
        for (int j = 0; j < 8; j++) {
            int ci = k8 * 8 + j;
            int ct = ci >> 4, jj = ci & 15, q = jj >> 2, r = jj & 3;
            int idx = (ct * 4 + (n >> 4)) * 256 + (q * 16 + (n & 15)) * 4 + r;
            vals[j] = (_Float16)(red[0][idx] + red[1][idx] + red[2][idx] + red[3][idx]);
        }
        *(f16x8*)(Yf + ((size_t)b * N_ + n0 + n) * CI_ + k8 * 8) = *(f16x8*)vals;
    }
}

// ---------------------------------------------------------------------------
// K3: out[b][c][n] = W_w @ Y^T + W_b + x (residual).
// ---------------------------------------------------------------------------
__global__ __launch_bounds__(256) void k_out(
    const _Float16* __restrict__ wW, const float* __restrict__ Wb,
    const _Float16* __restrict__ Yf, const float* __restrict__ x,
    float* __restrict__ out)
{
    int b = blockIdx.y, n0 = blockIdx.x * 64;
    int tid = threadIdx.x, wave = tid >> 6, lane = tid & 63;
    int l16 = lane & 15, quad = lane >> 4;
    f16x8 Af[2][2];
#pragma unroll
    for (int rt = 0; rt < 2; rt++)
#pragma unroll
        for (int kc = 0; kc < 2; kc++)
            Af[rt][kc] = *(const f16x8*)(wW + (size_t)(wave * 32 + rt * 16 + l16) * CI_ + kc * 32 + quad * 8);
    f32x4 acc[2][4] = {};
#pragma unroll
    for (int t = 0; t < 4; t++) {
        const _Float16* yp = Yf + ((size_t)b * N_ + n0 + t * 16 + l16) * CI_;
        f16x8 b0 = *(const f16x8*)(yp + quad * 8);
        f16x8 b1 = *(const f16x8*)(yp + 32 + quad * 8);
#pragma unroll
        for (int rt = 0; rt < 2; rt++) {
            acc[rt][t] = __builtin_amdgcn_mfma_f32_16x16x32_f16(Af[rt][0], b0, acc[rt][t], 0, 0, 0);
            acc[rt][t] = __builtin_amdgcn_mfma_f32_16x16x32_f16(Af[rt][1], b1, acc[rt][t], 0, 0, 0);
        }
    }
#pragma unroll
    for (int rt = 0; rt < 2; rt++)
#pragma unroll
        for (int t = 0; t < 4; t++)
#pragma unroll
            for (int r = 0; r < 4; r++) {
                int c = wave * 32 + rt * 16 + quad * 4 + r;
                size_t o = ((size_t)b * C_ + c) * N_ + n0 + t * 16 + l16;
                out[o] = acc[rt][t][r] + Wb[c] + x[o];
            }
}

// ---------------------------------------------------------------------------
extern "C" void kernel_launch(void* const* d_in, const int* in_sizes, int n_in,
                              void* d_out, int out_size, void* d_ws, size_t ws_size,
                              hipStream_t stream)
{
    const float* x    = (const float*)d_in[0];
    const float* g_w  = (const float*)d_in[1];
    const float* g_b  = (const float*)d_in[2];
    const float* th_w = (const float*)d_in[3];
    const float* th_b = (const float*)d_in[4];
    const float* ph_w = (const float*)d_in[5];
    const float* ph_b = (const float*)d_in[6];
    const float* W_w  = (const float*)d_in[7];
    const float* W_b  = (const float*)d_in[8];
    float* out = (float*)d_out;

    char* ws = (char*)d_ws;
    _Float16* xT  = (_Float16*)(ws);                  // [B][N][C]  8 MiB
    _Float16* thS = (_Float16*)(ws + 8388608);        // swizzled   4 MiB
    _Float16* phS = (_Float16*)(ws + 12582912);       // swizzled   4 MiB
    _Float16* gS  = (_Float16*)(ws + 16777216);       // swizzled   4 MiB
    _Float16* Yf  = (_Float16*)(ws + 20971520);       // [B][N][CI] 4 MiB
    float*    nl2d= (float*)   (ws + 25165824);       // [B][N]     128 KiB
    _Float16* wTh = (_Float16*)(ws + 25296896);
    _Float16* wPh = (_Float16*)(ws + 25313280);
    _Float16* wG  = (_Float16*)(ws + 25329664);
    _Float16* wW  = (_Float16*)(ws + 25346048);       // end ~25.4 MiB

    hipLaunchKernelGGL(k_transpose, dim3(64, 2, 8), dim3(256), 0, stream, x, xT);
    hipLaunchKernelGGL(k_wconv, dim3(128), dim3(256), 0, stream,
                       th_w, ph_w, g_w, W_w, wTh, wPh, wG, wW);
    hipLaunchKernelGGL(k_proj, dim3(64, 8), dim3(256), 0, stream,
                       xT, wTh, wPh, wG, th_b, ph_b, g_b, thS, phS, gS);
    hipLaunchKernelGGL(k_stats, dim3(64, 8), dim3(512), 0, stream, thS, phS, nl2d);
    hipLaunchKernelGGL(k_attn, dim3(64, 8), dim3(512), 0, stream, thS, phS, gS, nl2d, Yf);
    hipLaunchKernelGGL(k_out, dim3(64, 8), dim3(256), 0, stream, wW, W_b, Yf, x, out);
}